// Round 6
// baseline (756.501 us; speedup 1.0000x reference)
//
#include <hip/hip_runtime.h>
#include <stdint.h>
#include <stddef.h>

typedef __attribute__((ext_vector_type(4))) float f32x4;
typedef __attribute__((ext_vector_type(4))) int   i32x4;

constexpr int B = 4, P = 48000, C = 64, NY = 496, NX = 432, CMAP = 16;
constexpr int CT  = C + CMAP;            // 80 output channels
constexpr int X4  = NX / 4;              // 108 float4 groups per full row
constexpr int CQ  = C / 4;               // 16 channel quads
constexpr int XH  = NX / 2;              // 216: half-row for map LDS tile
constexpr int XH4 = XH / 4;              // 54
constexpr size_t PL = (size_t)NY * NX;   // 214,272 channel-plane stride
constexpr size_t OUT_FLOATS = (size_t)B * CT * PL;      // 68,567,040
constexpr size_t OUT_BYTES  = OUT_FLOATS * 4;           // 274,268,160
constexpr int    NQ   = (int)(OUT_FLOATS / 4);          // 17,141,760 quads
constexpr int    CPYG = 2048;
constexpr int    STEP = CPYG * 256;

// Pass A: build inverse map cell -> point id (cells unique by construction)
__global__ void scatter_inv_kernel(const int* __restrict__ coords,
                                   int* __restrict__ inv) {
    int p = blockIdx.x * blockDim.x + threadIdx.x;
    if (p >= P) return;
    const int4 cd = ((const int4*)coords)[p];     // (b, 0, y, x)
    inv[(cd.x * NY + cd.z) * NX + cd.w] = p;
}

// ---------------- PROBES (write only to ws canvas region) ----------------
// Probe C: linear device-wide sweep, 6 passes over 274 MB (1.65 GB issued).
// Positive control: should match fill/copy rate (~6 TB/s -> ~260 us).
__global__ void __launch_bounds__(256) probe_linear_kernel(
        f32x4* __restrict__ ws4) {
    #pragma unroll 1
    for (int pass = 0; pass < 6; ++pass) {
        f32x4 v; v.x = v.y = v.z = v.w = (float)(pass + 1);
        #pragma unroll 1
        for (int q = blockIdx.x * 256 + threadIdx.x; q < NQ; q += STEP)
            __builtin_nontemporal_store(v, &ws4[q]);
    }
}

// Probe A: EXACT vox plane-strided store pattern, stores only, 5 passes
// (1.10 GB issued). Isolates the write pattern from loads/dependencies.
__global__ void __launch_bounds__(256) probe_voxpat_kernel(
        float* __restrict__ ws) {
    const int x4 = threadIdx.x & 127;
    if (x4 >= X4) return;
    const int y   = (blockIdx.y << 1) | (threadIdx.x >> 7);
    const int bcq = blockIdx.z;
    const int cq  = bcq & (CQ - 1);
    const int b   = bcq >> 4;
    float* ob = ws + (((size_t)b * CT + cq * 4) * NY + y) * NX + x4 * 4;
    #pragma unroll 1
    for (int pass = 0; pass < 5; ++pass) {
        f32x4 s; s.x = s.y = s.z = s.w = (float)pass;
        __builtin_nontemporal_store(s, (f32x4*)(ob));
        __builtin_nontemporal_store(s, (f32x4*)(ob + PL));
        __builtin_nontemporal_store(s, (f32x4*)(ob + 2 * PL));
        __builtin_nontemporal_store(s, (f32x4*)(ob + 3 * PL));
    }
}

// Probe B: full vox semantics (inv load + gathers + stores), 5 passes.
// x4 rotated per pass so the inv/vox loads cannot be hoisted; stores stay
// at a fixed address (pattern identical to Probe A). B - A = load cost.
__global__ void __launch_bounds__(256) probe_voxfull_kernel(
        const float* __restrict__ vox, const int* __restrict__ inv,
        float* __restrict__ ws) {
    const int x4 = threadIdx.x & 127;
    if (x4 >= X4) return;
    const int y   = (blockIdx.y << 1) | (threadIdx.x >> 7);
    const int bcq = blockIdx.z;
    const int cq  = bcq & (CQ - 1);
    const int b   = bcq >> 4;
    float* ob = ws + (((size_t)b * CT + cq * 4) * NY + y) * NX + x4 * 4;
    const f32x4* vox4 = (const f32x4*)vox;
    #pragma unroll 1
    for (int pass = 0; pass < 5; ++pass) {
        int xr = x4 + pass; if (xr >= X4) xr -= X4;
        i32x4 p4 = ((const i32x4*)inv)[(b * NY + y) * X4 + xr];
        f32x4 r0 = (f32x4)0.f, r1 = (f32x4)0.f, r2 = (f32x4)0.f, r3 = (f32x4)0.f;
        if ((p4.x & p4.y & p4.z & p4.w) >= 0) {
            if (p4.x >= 0) r0 = vox4[(size_t)p4.x * CQ + cq];
            if (p4.y >= 0) r1 = vox4[(size_t)p4.y * CQ + cq];
            if (p4.z >= 0) r2 = vox4[(size_t)p4.z * CQ + cq];
            if (p4.w >= 0) r3 = vox4[(size_t)p4.w * CQ + cq];
        }
        f32x4 s;
        s.x = r0.x; s.y = r1.x; s.z = r2.x; s.w = r3.x;
        __builtin_nontemporal_store(s, (f32x4*)(ob));
        s.x = r0.y; s.y = r1.y; s.z = r2.y; s.w = r3.y;
        __builtin_nontemporal_store(s, (f32x4*)(ob + PL));
        s.x = r0.z; s.y = r1.z; s.z = r2.z; s.w = r3.z;
        __builtin_nontemporal_store(s, (f32x4*)(ob + 2 * PL));
        s.x = r0.w; s.y = r1.w; s.z = r2.w; s.w = r3.w;
        __builtin_nontemporal_store(s, (f32x4*)(ob + 3 * PL));
    }
}

// ---------------- real kernels (r5 structure, unchanged) ----------------
__global__ void __launch_bounds__(256) vox_fill_kernel(
        const float* __restrict__ vox, const int* __restrict__ inv,
        float* __restrict__ out) {
    const int x4  = threadIdx.x & 127;
    if (x4 >= X4) return;
    const int y   = (blockIdx.y << 1) | (threadIdx.x >> 7);
    const int bcq = blockIdx.z;
    const int cq  = bcq & (CQ - 1);
    const int b   = bcq >> 4;
    const int c0  = cq * 4;

    i32x4 p4 = ((const i32x4*)inv)[(b * NY + y) * X4 + x4];

    f32x4 r0 = (f32x4)0.f, r1 = (f32x4)0.f, r2 = (f32x4)0.f, r3 = (f32x4)0.f;
    if ((p4.x & p4.y & p4.z & p4.w) >= 0) {
        const f32x4* vox4 = (const f32x4*)vox;
        if (p4.x >= 0) r0 = vox4[(size_t)p4.x * CQ + cq];
        if (p4.y >= 0) r1 = vox4[(size_t)p4.y * CQ + cq];
        if (p4.z >= 0) r2 = vox4[(size_t)p4.z * CQ + cq];
        if (p4.w >= 0) r3 = vox4[(size_t)p4.w * CQ + cq];
    }

    float* ob = out + (((size_t)b * CT + c0) * NY + y) * NX + x4 * 4;
    f32x4 s;
    s.x = r0.x; s.y = r1.x; s.z = r2.x; s.w = r3.x;
    __builtin_nontemporal_store(s, (f32x4*)(ob));
    s.x = r0.y; s.y = r1.y; s.z = r2.y; s.w = r3.y;
    __builtin_nontemporal_store(s, (f32x4*)(ob + PL));
    s.x = r0.z; s.y = r1.z; s.z = r2.z; s.w = r3.z;
    __builtin_nontemporal_store(s, (f32x4*)(ob + 2 * PL));
    s.x = r0.w; s.y = r1.w; s.z = r2.w; s.w = r3.w;
    __builtin_nontemporal_store(s, (f32x4*)(ob + 3 * PL));
}

__global__ void __launch_bounds__(256) map_tile_kernel(
        const float* __restrict__ map, float* __restrict__ out) {
    __shared__ __align__(16) float m_s[2][CMAP][XH + 4];

    const int tid  = threadIdx.x;
    const int half = blockIdx.x;
    const int y0   = blockIdx.y << 1;
    const int b    = blockIdx.z;
    const int x0   = half * XH;

    const f32x4* map4 = (const f32x4*)map;
    #pragma unroll
    for (int k = 0; k < 7; ++k) {
        int idx = k * 256 + tid;
        if (idx < XH * 8) {
            int xh = idx >> 3, r = idx & 7, yy = r >> 2, q = r & 3;
            f32x4 mv = map4[((size_t)(b * NX + x0 + xh) * NY + y0 + yy) * 4 + q];
            m_s[yy][q * 4 + 0][xh] = mv.x;
            m_s[yy][q * 4 + 1][xh] = mv.y;
            m_s[yy][q * 4 + 2][xh] = mv.z;
            m_s[yy][q * 4 + 3][xh] = mv.w;
        }
    }
    __syncthreads();

    const size_t out_base = ((size_t)b * CT + C) * PL + (size_t)y0 * NX + x0;
    #pragma unroll
    for (int k = 0; k < 8; ++k) {
        int idx = k * 256 + tid;
        int sl  = idx & 63;
        int cmy = idx >> 6;
        int cm  = cmy >> 1, yy = cmy & 1;
        if (sl < XH4) {
            f32x4 v = *(const f32x4*)&m_s[yy][cm][sl * 4];
            __builtin_nontemporal_store(v,
                (f32x4*)(out + out_base + (size_t)cm * PL
                             + (size_t)yy * NX + sl * 4));
        }
    }
}

// ---------------- fallbacks ----------------
__global__ void zero_vox_region_kernel(float* __restrict__ out) {
    int g = blockIdx.x * 256 + threadIdx.x;
    if (g >= B * C * NY * X4) return;
    int x4   = g % X4;
    int rest = g / X4;
    int y  = rest % NY;
    int bc = rest / NY;
    int c  = bc & (C - 1);
    int b  = bc >> 6;
    *(f32x4*)(out + (((size_t)b * CT + c) * NY + y) * NX + x4 * 4) = (f32x4)0.f;
}

__global__ void scatter_direct_kernel(const float* __restrict__ vox,
                                      const int* __restrict__ coords,
                                      float* __restrict__ out) {
    int p = blockIdx.x;
    int c = threadIdx.x;
    const int4 cd = ((const int4*)coords)[p];
    out[(((size_t)cd.x * CT + c) * NY + cd.z) * NX + cd.w] = vox[(size_t)p * C + c];
}

__global__ void map_only_kernel(const float* __restrict__ map,
                                float* __restrict__ out) {
    int g = blockIdx.x * 256 + threadIdx.x;
    if (g >= B * CMAP * NY * NX) return;
    int x    = g % NX;
    int rest = g / NX;
    int y  = rest % NY;
    int bc = rest / NY;
    int cm = bc & (CMAP - 1);
    int b  = bc >> 4;
    out[((size_t)b * CT + C + cm) * PL + (size_t)y * NX + x] =
        map[((size_t)(b * NX + x) * NY + y) * CMAP + cm];
}

extern "C" void kernel_launch(void* const* d_in, const int* in_sizes, int n_in,
                              void* d_out, int out_size, void* d_ws, size_t ws_size,
                              hipStream_t stream) {
    const float* vox    = (const float*)d_in[0];   // (P, 64) float32
    const int*   coords = (const int*)d_in[1];     // (P, 4) int32
    const float* map    = (const float*)d_in[3];   // (B, NX, NY, CMAP) float32
    float* out = (float*)d_out;                    // (B, 80, NY, NX) float32

    const size_t inv_bytes = (size_t)B * NY * NX * sizeof(int);  // 3.43 MB

    if (ws_size >= OUT_BYTES + inv_bytes) {
        // Measurement round: probes (to ws scratch) + real path (to out).
        float* ws_f = (float*)d_ws;
        int*   inv  = (int*)((char*)d_ws + OUT_BYTES);
        (void)hipMemsetAsync(inv, 0xFF, inv_bytes, stream);      // all -1
        scatter_inv_kernel<<<(P + 255) / 256, 256, 0, stream>>>(coords, inv);
        probe_linear_kernel<<<CPYG, 256, 0, stream>>>((f32x4*)ws_f);
        probe_voxpat_kernel<<<dim3(1, NY / 2, B * CQ), 256, 0, stream>>>(ws_f);
        probe_voxfull_kernel<<<dim3(1, NY / 2, B * CQ), 256, 0, stream>>>(
            vox, inv, ws_f);
        vox_fill_kernel<<<dim3(1, NY / 2, B * CQ), 256, 0, stream>>>(vox, inv, out);
        map_tile_kernel<<<dim3(2, NY / 2, B), 256, 0, stream>>>(map, out);
    } else if (ws_size >= inv_bytes) {
        int* inv = (int*)d_ws;
        (void)hipMemsetAsync(inv, 0xFF, inv_bytes, stream);      // all -1
        scatter_inv_kernel<<<(P + 255) / 256, 256, 0, stream>>>(coords, inv);
        vox_fill_kernel<<<dim3(1, NY / 2, B * CQ), 256, 0, stream>>>(vox, inv, out);
        map_tile_kernel<<<dim3(2, NY / 2, B), 256, 0, stream>>>(map, out);
    } else {
        zero_vox_region_kernel<<<(B * C * NY * X4 + 255) / 256, 256, 0, stream>>>(out);
        scatter_direct_kernel<<<P, 64, 0, stream>>>(vox, coords, out);
        map_only_kernel<<<(B * CMAP * NY * NX + 255) / 256, 256, 0, stream>>>(map, out);
    }
}